// Round 5
// baseline (558.271 us; speedup 1.0000x reference)
//
#include <hip/hip_runtime.h>

// GCN forward: h = relu(spmm(x@w1)+b1); out = spmm(h@w2)+b2
// CSR built on-device per launch via 2-level bucketed placement (coalesced writes).
// Intermediates bf16-packed. GEMMs: no-LDS direct-register bf16 MFMA.

typedef unsigned int uint;
typedef unsigned short ushort;
using bf16x8 = __attribute__((ext_vector_type(8))) short;
using f32x4  = __attribute__((ext_vector_type(4))) float;

union U8 { bf16x8 v; uint4 q; };

#define CHUNK 16384   // edges per partition block
#define BW    256     // rows per bucket

__device__ inline uint f2bf(float f) {
  uint u = __float_as_uint(f);
  return (u + 0x7fffu + ((u >> 16) & 1u)) >> 16;   // RNE
}
__device__ inline uint pkbf(float lo, float hi) { return f2bf(lo) | (f2bf(hi) << 16); }
__device__ inline float bf_lo(uint u) { return __uint_as_float(u << 16); }
__device__ inline float bf_hi(uint u) { return __uint_as_float(u & 0xffff0000u); }

// ---------------- weight transpose+cast (tiny) ----------------
__global__ void k_tr_w1(const float* __restrict__ w, ushort* __restrict__ wt) {
  int idx = blockIdx.x * 256 + threadIdx.x;      // 32768 = 256*128
  int k = idx >> 7, n = idx & 127;
  wt[n * 256 + k] = (ushort)f2bf(w[idx]);
}
__global__ void k_tr_w2(const float* __restrict__ w, ushort* __restrict__ wt) {
  int idx = blockIdx.x * 256 + threadIdx.x;      // 8192 = 128*64
  int k = idx >> 6, n = idx & 63;
  wt[n * 128 + k] = (ushort)f2bf(w[idx]);
}

// ---------------- degree + row-pointer ----------------
__global__ void k_zero(int* __restrict__ p, int n) {
  int i = blockIdx.x * blockDim.x + threadIdx.x;
  if (i < n) p[i] = 0;
}

__global__ void k_count(const int* __restrict__ row, int* __restrict__ deg, int ne) {
  int e = blockIdx.x * blockDim.x + threadIdx.x;
  if (e < ne) atomicAdd(&deg[row[e]], 1);
}

__global__ __launch_bounds__(256)
void k_scan_block(const int* __restrict__ deg, int* __restrict__ out,
                  int* __restrict__ bsums, int n) {
  __shared__ int sd[256];
  int t = threadIdx.x;
  int base = blockIdx.x * 1024 + t * 4;
  int v0 = (base + 0 < n) ? deg[base + 0] : 0;
  int v1 = (base + 1 < n) ? deg[base + 1] : 0;
  int v2 = (base + 2 < n) ? deg[base + 2] : 0;
  int v3 = (base + 3 < n) ? deg[base + 3] : 0;
  int s = v0 + v1 + v2 + v3;
  sd[t] = s;
  __syncthreads();
  for (int off = 1; off < 256; off <<= 1) {
    int x = (t >= off) ? sd[t - off] : 0;
    __syncthreads();
    sd[t] += x;
    __syncthreads();
  }
  int excl = sd[t] - s;
  if (base + 0 < n) out[base + 0] = excl;
  if (base + 1 < n) out[base + 1] = excl + v0;
  if (base + 2 < n) out[base + 2] = excl + v0 + v1;
  if (base + 3 < n) out[base + 3] = excl + v0 + v1 + v2;
  if (t == 255) bsums[blockIdx.x] = sd[255];
}

__global__ __launch_bounds__(256)
void k_scan_sums(int* __restrict__ bsums, int nb) {
  __shared__ int sd[256];
  int t = threadIdx.x;
  int v = (t < nb) ? bsums[t] : 0;
  sd[t] = v;
  __syncthreads();
  for (int off = 1; off < 256; off <<= 1) {
    int x = (t >= off) ? sd[t - off] : 0;
    __syncthreads();
    sd[t] += x;
    __syncthreads();
  }
  if (t < nb) bsums[t] = sd[t] - v;
}

__global__ void k_scan_add(int* __restrict__ rp, const int* __restrict__ bsums, int n) {
  int i = blockIdx.x * blockDim.x + threadIdx.x;
  if (i < n) rp[i] += bsums[i >> 10];
}

// ---------------- bucketed CSR placement ----------------
// P1: per-block histogram over row-buckets
__global__ __launch_bounds__(256)
void k_p1_hist(const int* __restrict__ row, int* __restrict__ bh, int nb, int ne) {
  __shared__ int hist[512];
  int t = threadIdx.x;
  for (int i = t; i < 512; i += 256) hist[i] = 0;
  __syncthreads();
  int base = blockIdx.x * CHUNK;
  for (int i = t; i < CHUNK; i += 256) {
    int e = base + i;
    if (e < ne) atomicAdd(&hist[row[e] >> 8], 1);
  }
  __syncthreads();
  for (int i = t; i < nb; i += 256) bh[blockIdx.x * nb + i] = hist[i];
}

// P2: per-bucket exclusive prefix across blocks (single block launch)
__global__ __launch_bounds__(512)
void k_p2_prefix(int* __restrict__ bh, int nb, int nblk) {
  int t = threadIdx.x;
  if (t >= nb) return;
  int run = 0;
  for (int b = 0; b < nblk; ++b) {
    int v = bh[b * nb + t];
    bh[b * nb + t] = run;
    run += v;
  }
}

// P3: partition edges into bucket runs (clustered writes)
__global__ __launch_bounds__(256)
void k_p3_part(const int* __restrict__ row, const int* __restrict__ col,
               const float* __restrict__ vals, const int* __restrict__ bh,
               const int* __restrict__ rp, uint2* __restrict__ tmp,
               int nb, int ne) {
  __shared__ int cur[512];
  int t = threadIdx.x;
  for (int i = t; i < nb; i += 256)
    cur[i] = rp[i << 8] + bh[blockIdx.x * nb + i];   // bucketBase == rp[g*BW]
  __syncthreads();
  int base = blockIdx.x * CHUNK;
  for (int i = t; i < CHUNK; i += 256) {
    int e = base + i;
    if (e < ne) {
      int r = row[e];
      int p = atomicAdd(&cur[r >> 8], 1);
      uint2 ev;
      ev.x = ((uint)(r & 255) << 17) | (uint)col[e];
      ev.y = __float_as_uint(vals[e]);
      tmp[p] = ev;
    }
  }
}

// P4: within-bucket exact placement (one block per bucket)
__global__ __launch_bounds__(256)
void k_p4_place(const uint2* __restrict__ tmp, const int* __restrict__ rp,
                uint2* __restrict__ edges, int n, int ne) {
  __shared__ int rowcur[256];
  int g  = blockIdx.x;
  int t  = threadIdx.x;
  int r0 = g << 8;
  int row = r0 + t;
  rowcur[t] = (row < n) ? rp[row] : 0;
  __syncthreads();
  int s  = rp[r0];
  int e1 = (r0 + 256 < n) ? rp[r0 + 256] : ne;
  for (int i = s + t; i < e1; i += 256) {
    uint2 ev = tmp[i];
    int lr = (int)(ev.x >> 17);
    uint c = ev.x & 0x1FFFFu;
    int p = atomicAdd(&rowcur[lr], 1);
    edges[p] = make_uint2(c, ev.y);
  }
}

// ---------------- GEMM1 (MFMA): h_bf16[M,128] = x[M,256] @ w1[256,128] ----------------
__global__ __launch_bounds__(256)
void gemm1_mfma(const float* __restrict__ A, const ushort* __restrict__ Bt,
                uint* __restrict__ C, int M) {
  const int tid  = threadIdx.x;
  const int wid  = tid >> 6;
  const int lane = tid & 63;
  const int lr   = lane & 15;
  const int lk   = lane >> 4;
  const int m0   = blockIdx.x * 128 + wid * 32;

  f32x4 acc[2][8];
#pragma unroll
  for (int mf = 0; mf < 2; ++mf)
#pragma unroll
    for (int nf = 0; nf < 8; ++nf) acc[mf][nf] = (f32x4){0.f, 0.f, 0.f, 0.f};

  const int row0 = min(m0 + lr,      M - 1);
  const int row1 = min(m0 + 16 + lr, M - 1);
  const float*  a0p = A + (size_t)row0 * 256 + lk * 8;
  const float*  a1p = A + (size_t)row1 * 256 + lk * 8;
  const ushort* bp  = Bt + lr * 256 + lk * 8;

#pragma unroll
  for (int kk = 0; kk < 8; ++kk) {
    float4 x0 = *(const float4*)(a0p + kk * 32);
    float4 x1 = *(const float4*)(a0p + kk * 32 + 4);
    float4 y0 = *(const float4*)(a1p + kk * 32);
    float4 y1 = *(const float4*)(a1p + kk * 32 + 4);
    U8 a0, a1;
    a0.q = make_uint4(pkbf(x0.x, x0.y), pkbf(x0.z, x0.w), pkbf(x1.x, x1.y), pkbf(x1.z, x1.w));
    a1.q = make_uint4(pkbf(y0.x, y0.y), pkbf(y0.z, y0.w), pkbf(y1.x, y1.y), pkbf(y1.z, y1.w));
    bf16x8 b[8];
#pragma unroll
    for (int nf = 0; nf < 8; ++nf)
      b[nf] = *(const bf16x8*)(bp + nf * 4096 + kk * 32);
#pragma unroll
    for (int nf = 0; nf < 8; ++nf) {
      acc[0][nf] = __builtin_amdgcn_mfma_f32_16x16x32_bf16(a0.v, b[nf], acc[0][nf], 0, 0, 0);
      acc[1][nf] = __builtin_amdgcn_mfma_f32_16x16x32_bf16(a1.v, b[nf], acc[1][nf], 0, 0, 0);
    }
  }

  const bool evenl = (lr & 1) == 0;
#pragma unroll
  for (int mf = 0; mf < 2; ++mf)
#pragma unroll
    for (int nf = 0; nf < 8; ++nf)
#pragma unroll
      for (int j = 0; j < 4; ++j) {
        float own = acc[mf][nf][j];
        float oth = __shfl_xor(own, 1);
        int row = m0 + mf * 16 + lk * 4 + j;
        if (evenl && row < M)
          C[(size_t)row * 64 + nf * 8 + (lr >> 1)] = pkbf(own, oth);
      }
}

// ---------------- GEMM2 (MFMA): h2_bf16[M,64] = agg_bf16[M,128] @ w2[128,64] ----------------
__global__ __launch_bounds__(256)
void gemm2_mfma(const uint* __restrict__ A, const ushort* __restrict__ Bt,
                uint* __restrict__ C, int M) {
  const int tid  = threadIdx.x;
  const int wid  = tid >> 6;
  const int lane = tid & 63;
  const int lr   = lane & 15;
  const int lk   = lane >> 4;
  const int m0   = blockIdx.x * 128 + wid * 32;

  f32x4 acc[2][4];
#pragma unroll
  for (int mf = 0; mf < 2; ++mf)
#pragma unroll
    for (int nf = 0; nf < 4; ++nf) acc[mf][nf] = (f32x4){0.f, 0.f, 0.f, 0.f};

  const int row0 = min(m0 + lr,      M - 1);
  const int row1 = min(m0 + 16 + lr, M - 1);
  const ushort* A16 = (const ushort*)A;
  const ushort* a0p = A16 + (size_t)row0 * 128 + lk * 8;
  const ushort* a1p = A16 + (size_t)row1 * 128 + lk * 8;
  const ushort* bp  = Bt + lr * 128 + lk * 8;

#pragma unroll
  for (int kk = 0; kk < 4; ++kk) {
    bf16x8 a0 = *(const bf16x8*)(a0p + kk * 32);
    bf16x8 a1 = *(const bf16x8*)(a1p + kk * 32);
    bf16x8 b[4];
#pragma unroll
    for (int nf = 0; nf < 4; ++nf)
      b[nf] = *(const bf16x8*)(bp + nf * 2048 + kk * 32);
#pragma unroll
    for (int nf = 0; nf < 4; ++nf) {
      acc[0][nf] = __builtin_amdgcn_mfma_f32_16x16x32_bf16(a0, b[nf], acc[0][nf], 0, 0, 0);
      acc[1][nf] = __builtin_amdgcn_mfma_f32_16x16x32_bf16(a1, b[nf], acc[1][nf], 0, 0, 0);
    }
  }

  const bool evenl = (lr & 1) == 0;
#pragma unroll
  for (int mf = 0; mf < 2; ++mf)
#pragma unroll
    for (int nf = 0; nf < 4; ++nf)
#pragma unroll
      for (int j = 0; j < 4; ++j) {
        float own = acc[mf][nf][j];
        float oth = __shfl_xor(own, 1);
        int row = m0 + mf * 16 + lk * 4 + j;
        if (evenl && row < M)
          C[(size_t)row * 32 + nf * 8 + (lr >> 1)] = pkbf(own, oth);
      }
}

// ---------------- SPMM1 + relu(+b1): one wave/row, 128 feats bf16 ----------------
__global__ __launch_bounds__(256)
void k_spmm1(const int* __restrict__ rp, const int* __restrict__ deg,
             const uint2* __restrict__ edges, const uint* __restrict__ h,
             const float* __restrict__ b1, uint* __restrict__ agg, int n) {
  int r = blockIdx.x * 4 + (threadIdx.x >> 6);
  if (r >= n) return;
  int lane = threadIdx.x & 63;
  int s = rp[r], d = deg[r];
  float a0 = 0.f, a1 = 0.f;            // feats 2*lane, 2*lane+1
  int t = 0;
  for (; t + 4 <= d; t += 4) {
    uint2 e0 = edges[s + t + 0];
    uint2 e1 = edges[s + t + 1];
    uint2 e2 = edges[s + t + 2];
    uint2 e3 = edges[s + t + 3];
    uint u0 = h[(size_t)e0.x * 64 + lane];
    uint u1 = h[(size_t)e1.x * 64 + lane];
    uint u2 = h[(size_t)e2.x * 64 + lane];
    uint u3 = h[(size_t)e3.x * 64 + lane];
    float v0 = __uint_as_float(e0.y), v1 = __uint_as_float(e1.y);
    float v2 = __uint_as_float(e2.y), v3 = __uint_as_float(e3.y);
    a0 = fmaf(v0, bf_lo(u0), a0); a1 = fmaf(v0, bf_hi(u0), a1);
    a0 = fmaf(v1, bf_lo(u1), a0); a1 = fmaf(v1, bf_hi(u1), a1);
    a0 = fmaf(v2, bf_lo(u2), a0); a1 = fmaf(v2, bf_hi(u2), a1);
    a0 = fmaf(v3, bf_lo(u3), a0); a1 = fmaf(v3, bf_hi(u3), a1);
  }
  for (; t < d; ++t) {
    uint2 e0 = edges[s + t];
    uint u0 = h[(size_t)e0.x * 64 + lane];
    float v0 = __uint_as_float(e0.y);
    a0 = fmaf(v0, bf_lo(u0), a0); a1 = fmaf(v0, bf_hi(u0), a1);
  }
  float2 bb = ((const float2*)b1)[lane];
  float r0 = fmaxf(a0 + bb.x, 0.f);
  float r1 = fmaxf(a1 + bb.y, 0.f);
  agg[(size_t)r * 64 + lane] = pkbf(r0, r1);
}

// ---------------- SPMM2 + b2: one wave/row, 2 half-wave edge workers ----------------
__global__ __launch_bounds__(256)
void k_spmm2(const int* __restrict__ rp, const int* __restrict__ deg,
             const uint2* __restrict__ edges, const uint* __restrict__ h2,
             const float* __restrict__ b2, float* __restrict__ out, int n) {
  int r = blockIdx.x * 4 + (threadIdx.x >> 6);
  if (r >= n) return;
  int lane = threadIdx.x & 63;
  int half = lane >> 5;
  int fl = lane & 31;                  // feat pair 2*fl, 2*fl+1
  int s = rp[r], d = deg[r];
  float a0 = 0.f, a1 = 0.f;
  int t = half;
  for (; t + 2 < d; t += 4) {
    uint2 e0 = edges[s + t];
    uint2 e1 = edges[s + t + 2];
    uint u0 = h2[(size_t)e0.x * 32 + fl];
    uint u1 = h2[(size_t)e1.x * 32 + fl];
    float v0 = __uint_as_float(e0.y), v1 = __uint_as_float(e1.y);
    a0 = fmaf(v0, bf_lo(u0), a0); a1 = fmaf(v0, bf_hi(u0), a1);
    a0 = fmaf(v1, bf_lo(u1), a0); a1 = fmaf(v1, bf_hi(u1), a1);
  }
  if (t < d) {
    uint2 e0 = edges[s + t];
    uint u0 = h2[(size_t)e0.x * 32 + fl];
    float v0 = __uint_as_float(e0.y);
    a0 = fmaf(v0, bf_lo(u0), a0); a1 = fmaf(v0, bf_hi(u0), a1);
  }
  a0 += __shfl_xor(a0, 32);
  a1 += __shfl_xor(a1, 32);
  if (half == 0) {
    float2 bb = ((const float2*)b2)[fl];
    ((float2*)out)[(size_t)r * 32 + fl] = make_float2(a0 + bb.x, a1 + bb.y);
  }
}

extern "C" void kernel_launch(void* const* d_in, const int* in_sizes, int n_in,
                              void* d_out, int out_size, void* d_ws, size_t ws_size,
                              hipStream_t stream) {
  const float* x        = (const float*)d_in[0];
  const float* w1       = (const float*)d_in[1];
  const float* b1       = (const float*)d_in[2];
  const float* w2       = (const float*)d_in[3];
  const float* b2       = (const float*)d_in[4];
  const int*   adj_row  = (const int*)d_in[5];
  const int*   adj_col  = (const int*)d_in[6];
  const float* adj_vals = (const float*)d_in[7];
  float* out = (float*)d_out;

  const int N  = in_sizes[0] / 256;   // 100000
  const int NE = in_sizes[5];         // 1600000

  const int NB   = (N + BW - 1) / BW;          // 391 row-buckets
  const int NBLK = (NE + CHUNK - 1) / CHUNK;   // 98 partition blocks

  char* p = (char*)d_ws;
  auto carve = [&](size_t bytes) {
    char* r = p;
    p += (bytes + 255) & ~(size_t)255;
    return (void*)r;
  };
  uint*   h      = (uint*)  carve((size_t)N * 64 * 4);     // bf16 [N][128]
  uint*   agg    = (uint*)  carve((size_t)N * 64 * 4);     // bf16 [N][128]
  uint2*  edges  = (uint2*) carve((size_t)NE * 8);         // {col, val}
  uint2*  tmp    = (uint2*) carve((size_t)NE * 8);         // bucket-partitioned
  int*    rp     = (int*)   carve((size_t)N * 4);
  int*    deg    = (int*)   carve((size_t)N * 4);
  int*    bh     = (int*)   carve((size_t)NBLK * NB * 4);  // per-(block,bucket) hist
  int*    bsums  = (int*)   carve(1024);
  ushort* w1t    = (ushort*)carve(128 * 256 * 2);          // bf16 [128][256]
  ushort* w2t    = (ushort*)carve(64 * 128 * 2);           // bf16 [64][128]
  uint*   h2     = h;                                      // bf16 [N][64], h dead after spmm1

  const int nb_scan = (N + 1023) / 1024;

  hipLaunchKernelGGL(k_tr_w1,      dim3(128),              dim3(256), 0, stream, w1, w1t);
  hipLaunchKernelGGL(k_tr_w2,      dim3(32),               dim3(256), 0, stream, w2, w2t);
  hipLaunchKernelGGL(k_zero,       dim3((N + 255) / 256),  dim3(256), 0, stream, deg, N);
  hipLaunchKernelGGL(k_count,      dim3((NE + 255) / 256), dim3(256), 0, stream, adj_row, deg, NE);
  hipLaunchKernelGGL(k_p1_hist,    dim3(NBLK),             dim3(256), 0, stream, adj_row, bh, NB, NE);
  hipLaunchKernelGGL(k_scan_block, dim3(nb_scan),          dim3(256), 0, stream, deg, rp, bsums, N);
  hipLaunchKernelGGL(k_scan_sums,  dim3(1),                dim3(256), 0, stream, bsums, nb_scan);
  hipLaunchKernelGGL(k_scan_add,   dim3((N + 255) / 256),  dim3(256), 0, stream, rp, bsums, N);
  hipLaunchKernelGGL(k_p2_prefix,  dim3(1),                dim3(512), 0, stream, bh, NB, NBLK);
  hipLaunchKernelGGL(k_p3_part,    dim3(NBLK),             dim3(256), 0, stream,
                     adj_row, adj_col, adj_vals, bh, rp, tmp, NB, NE);
  hipLaunchKernelGGL(k_p4_place,   dim3(NB),               dim3(256), 0, stream,
                     tmp, rp, edges, N, NE);

  hipLaunchKernelGGL(gemm1_mfma,   dim3((N + 127) / 128),  dim3(256), 0, stream, x, w1t, h, N);
  hipLaunchKernelGGL(k_spmm1,      dim3((N + 3) / 4),      dim3(256), 0, stream,
                     rp, deg, edges, h, b1, agg, N);
  hipLaunchKernelGGL(gemm2_mfma,   dim3((N + 127) / 128),  dim3(256), 0, stream, agg, w2t, h2, N);
  hipLaunchKernelGGL(k_spmm2,      dim3((N + 3) / 4),      dim3(256), 0, stream,
                     rp, deg, edges, h2, b2, out, N);
}

// Round 7
// 414.556 us; speedup vs baseline: 1.3467x; 1.3467x over previous
//
#include <hip/hip_runtime.h>

// GCN forward: h = relu(spmm(x@w1)+b1); out = spmm(h@w2)+b2
// CSR built per launch: bucket partition (128-row buckets, 2048-edge chunks)
// + per-bucket counting sort that also emits row pointers (no count/scan pass).
// Intermediates bf16-packed. GEMMs: no-LDS direct-register bf16 MFMA.

typedef unsigned int uint;
typedef unsigned short ushort;
using bf16x8 = __attribute__((ext_vector_type(8))) short;
using f32x4  = __attribute__((ext_vector_type(4))) float;

union U8 { bf16x8 v; uint4 q; };

#define CHUNK 2048    // edges per partition block
#define BW    128     // rows per bucket

__device__ inline uint f2bf(float f) {
  uint u = __float_as_uint(f);
  return (u + 0x7fffu + ((u >> 16) & 1u)) >> 16;   // RNE
}
__device__ inline uint pkbf(float lo, float hi) { return f2bf(lo) | (f2bf(hi) << 16); }
__device__ inline float bf_lo(uint u) { return __uint_as_float(u << 16); }
__device__ inline float bf_hi(uint u) { return __uint_as_float(u & 0xffff0000u); }

// ---------------- weight transpose+cast (fused, tiny) ----------------
__global__ void k_tr_w(const float* __restrict__ w1, ushort* __restrict__ w1t,
                       const float* __restrict__ w2, ushort* __restrict__ w2t) {
  int idx = blockIdx.x * 256 + threadIdx.x;
  if (idx < 32768) {               // 256x128
    int k = idx >> 7, n = idx & 127;
    w1t[n * 256 + k] = (ushort)f2bf(w1[idx]);
  } else {
    int j = idx - 32768;           // 128x64
    if (j < 8192) {
      int k = j >> 6, n = j & 63;
      w2t[n * 128 + k] = (ushort)f2bf(w2[j]);
    }
  }
}

// ---------------- P1: per-chunk histogram over row-buckets ----------------
__global__ __launch_bounds__(256)
void k_p1_hist(const int* __restrict__ row, int* __restrict__ bh,
               int nb, int nblk, int ne) {
  __shared__ int hist[1024];
  int t = threadIdx.x;
  for (int i = t; i < nb; i += 256) hist[i] = 0;
  __syncthreads();
  int base = blockIdx.x * CHUNK;
  int end  = min(base + CHUNK, ne);
  for (int i = base + t; i < end; i += 256)
    atomicAdd(&hist[row[i] >> 7], 1);
  __syncthreads();
  for (int i = t; i < nb; i += 256)
    bh[(size_t)i * nblk + blockIdx.x] = hist[i];   // transposed: [bucket][chunk]
}

// ---------------- P2a: per-bucket exclusive scan across chunks ----------------
__global__ __launch_bounds__(1024)
void k_p2a(int* __restrict__ bh, int* __restrict__ tot, int nblk) {
  __shared__ int sd[1024];
  int g = blockIdx.x, t = threadIdx.x;
  int v = (t < nblk) ? bh[(size_t)g * nblk + t] : 0;
  sd[t] = v;
  __syncthreads();
  for (int o = 1; o < 1024; o <<= 1) {
    int x = (t >= o) ? sd[t - o] : 0;
    __syncthreads();
    sd[t] += x;
    __syncthreads();
  }
  if (t < nblk) bh[(size_t)g * nblk + t] = sd[t] - v;
  if (t == 1023) tot[g] = sd[1023];
}

// ---------------- P2b: exclusive scan of bucket totals -> bucketBase ----------------
__global__ __launch_bounds__(1024)
void k_p2b(const int* __restrict__ tot, int* __restrict__ bucketBase, int nb) {
  __shared__ int sd[1024];
  int t = threadIdx.x;
  int v = (t < nb) ? tot[t] : 0;
  sd[t] = v;
  __syncthreads();
  for (int o = 1; o < 1024; o <<= 1) {
    int x = (t >= o) ? sd[t - o] : 0;
    __syncthreads();
    sd[t] += x;
    __syncthreads();
  }
  if (t < nb) bucketBase[t] = sd[t] - v;
}

// ---------------- P3: partition edges into bucket segments ----------------
__global__ __launch_bounds__(256)
void k_p3_part(const int* __restrict__ row, const int* __restrict__ col,
               const float* __restrict__ vals, const int* __restrict__ bh,
               const int* __restrict__ bucketBase, uint2* __restrict__ tmp,
               int nb, int nblk, int ne) {
  __shared__ int cur[1024];
  int t = threadIdx.x, blk = blockIdx.x;
  for (int i = t; i < nb; i += 256)
    cur[i] = bucketBase[i] + bh[(size_t)i * nblk + blk];
  __syncthreads();
  int base = blk * CHUNK;
  int end  = min(base + CHUNK, ne);
  for (int i = base + t; i < end; i += 256) {
    int r = row[i];
    int p = atomicAdd(&cur[r >> 7], 1);
    tmp[p] = make_uint2(((uint)(r & 127) << 17) | (uint)col[i],
                        __float_as_uint(vals[i]));
  }
}

// ---------------- P4: per-bucket counting sort; emits rp + final edges ----------------
__global__ __launch_bounds__(256)
void k_p4_sort(const uint2* __restrict__ tmp, const int* __restrict__ bucketBase,
               int* __restrict__ rp, uint2* __restrict__ edges,
               int ne, int nb) {
  __shared__ int hist[128];
  __shared__ int cur[128];
  int g = blockIdx.x, t = threadIdx.x;
  int base = bucketBase[g];
  int end  = (g + 1 < nb) ? bucketBase[g + 1] : ne;
  if (t < 128) hist[t] = 0;
  __syncthreads();
  for (int i = base + t; i < end; i += 256)
    atomicAdd(&hist[tmp[i].x >> 17], 1);
  __syncthreads();
  int v = (t < 128) ? hist[t] : 0;
  for (int o = 1; o < 128; o <<= 1) {
    int x = (t < 128 && t >= o) ? hist[t - o] : 0;
    __syncthreads();
    if (t < 128) hist[t] += x;
    __syncthreads();
  }
  if (t < 128) {
    int excl = hist[t] - v;
    rp[(g << 7) + t] = base + excl;   // rows >= N get rp = segment end (= NE at tail)
    cur[t] = base + excl;
  }
  __syncthreads();
  for (int i = base + t; i < end; i += 256) {
    uint2 ev = tmp[i];
    int lr = (int)(ev.x >> 17);
    int p = atomicAdd(&cur[lr], 1);
    edges[p] = make_uint2(ev.x & 0x1FFFFu, ev.y);
  }
}

// ---------------- GEMM1 (MFMA): h_bf16[M,128] = x[M,256] @ w1[256,128] ----------------
__global__ __launch_bounds__(256)
void gemm1_mfma(const float* __restrict__ A, const ushort* __restrict__ Bt,
                uint* __restrict__ C, int M) {
  const int tid  = threadIdx.x;
  const int wid  = tid >> 6;
  const int lane = tid & 63;
  const int lr   = lane & 15;
  const int lk   = lane >> 4;
  const int m0   = blockIdx.x * 128 + wid * 32;

  f32x4 acc[2][8];
#pragma unroll
  for (int mf = 0; mf < 2; ++mf)
#pragma unroll
    for (int nf = 0; nf < 8; ++nf) acc[mf][nf] = (f32x4){0.f, 0.f, 0.f, 0.f};

  const int row0 = min(m0 + lr,      M - 1);
  const int row1 = min(m0 + 16 + lr, M - 1);
  const float*  a0p = A + (size_t)row0 * 256 + lk * 8;
  const float*  a1p = A + (size_t)row1 * 256 + lk * 8;
  const ushort* bp  = Bt + lr * 256 + lk * 8;

#pragma unroll
  for (int kk = 0; kk < 8; ++kk) {
    float4 x0 = *(const float4*)(a0p + kk * 32);
    float4 x1 = *(const float4*)(a0p + kk * 32 + 4);
    float4 y0 = *(const float4*)(a1p + kk * 32);
    float4 y1 = *(const float4*)(a1p + kk * 32 + 4);
    U8 a0, a1;
    a0.q = make_uint4(pkbf(x0.x, x0.y), pkbf(x0.z, x0.w), pkbf(x1.x, x1.y), pkbf(x1.z, x1.w));
    a1.q = make_uint4(pkbf(y0.x, y0.y), pkbf(y0.z, y0.w), pkbf(y1.x, y1.y), pkbf(y1.z, y1.w));
    bf16x8 b[8];
#pragma unroll
    for (int nf = 0; nf < 8; ++nf)
      b[nf] = *(const bf16x8*)(bp + nf * 4096 + kk * 32);
#pragma unroll
    for (int nf = 0; nf < 8; ++nf) {
      acc[0][nf] = __builtin_amdgcn_mfma_f32_16x16x32_bf16(a0.v, b[nf], acc[0][nf], 0, 0, 0);
      acc[1][nf] = __builtin_amdgcn_mfma_f32_16x16x32_bf16(a1.v, b[nf], acc[1][nf], 0, 0, 0);
    }
  }

  const bool evenl = (lr & 1) == 0;
#pragma unroll
  for (int mf = 0; mf < 2; ++mf)
#pragma unroll
    for (int nf = 0; nf < 8; ++nf)
#pragma unroll
      for (int j = 0; j < 4; ++j) {
        float own = acc[mf][nf][j];
        float oth = __shfl_xor(own, 1);
        int row = m0 + mf * 16 + lk * 4 + j;
        if (evenl && row < M)
          C[(size_t)row * 64 + nf * 8 + (lr >> 1)] = pkbf(own, oth);
      }
}

// ---------------- GEMM2 (MFMA): h2_bf16[M,64] = agg_bf16[M,128] @ w2[128,64] ----------------
__global__ __launch_bounds__(256)
void gemm2_mfma(const uint* __restrict__ A, const ushort* __restrict__ Bt,
                uint* __restrict__ C, int M) {
  const int tid  = threadIdx.x;
  const int wid  = tid >> 6;
  const int lane = tid & 63;
  const int lr   = lane & 15;
  const int lk   = lane >> 4;
  const int m0   = blockIdx.x * 128 + wid * 32;

  f32x4 acc[2][4];
#pragma unroll
  for (int mf = 0; mf < 2; ++mf)
#pragma unroll
    for (int nf = 0; nf < 4; ++nf) acc[mf][nf] = (f32x4){0.f, 0.f, 0.f, 0.f};

  const int row0 = min(m0 + lr,      M - 1);
  const int row1 = min(m0 + 16 + lr, M - 1);
  const ushort* A16 = (const ushort*)A;
  const ushort* a0p = A16 + (size_t)row0 * 128 + lk * 8;
  const ushort* a1p = A16 + (size_t)row1 * 128 + lk * 8;
  const ushort* bp  = Bt + lr * 128 + lk * 8;

#pragma unroll
  for (int kk = 0; kk < 4; ++kk) {
    bf16x8 a0 = *(const bf16x8*)(a0p + kk * 32);
    bf16x8 a1 = *(const bf16x8*)(a1p + kk * 32);
    bf16x8 b[4];
#pragma unroll
    for (int nf = 0; nf < 4; ++nf)
      b[nf] = *(const bf16x8*)(bp + nf * 2048 + kk * 32);
#pragma unroll
    for (int nf = 0; nf < 4; ++nf) {
      acc[0][nf] = __builtin_amdgcn_mfma_f32_16x16x32_bf16(a0, b[nf], acc[0][nf], 0, 0, 0);
      acc[1][nf] = __builtin_amdgcn_mfma_f32_16x16x32_bf16(a1, b[nf], acc[1][nf], 0, 0, 0);
    }
  }

  const bool evenl = (lr & 1) == 0;
#pragma unroll
  for (int mf = 0; mf < 2; ++mf)
#pragma unroll
    for (int nf = 0; nf < 4; ++nf)
#pragma unroll
      for (int j = 0; j < 4; ++j) {
        float own = acc[mf][nf][j];
        float oth = __shfl_xor(own, 1);
        int row = m0 + mf * 16 + lk * 4 + j;
        if (evenl && row < M)
          C[(size_t)row * 32 + nf * 8 + (lr >> 1)] = pkbf(own, oth);
      }
}

// ---------------- SPMM1 + relu(+b1): one wave/row, 8 gathers in flight ----------------
__global__ __launch_bounds__(256)
void k_spmm1(const int* __restrict__ rp, const uint2* __restrict__ edges,
             const uint* __restrict__ h, const float* __restrict__ b1,
             uint* __restrict__ agg, int n) {
  int r = blockIdx.x * 4 + (threadIdx.x >> 6);
  if (r >= n) return;
  int lane = threadIdx.x & 63;
  int s = rp[r], e = rp[r + 1];
  float a0 = 0.f, a1 = 0.f;            // feats 2*lane, 2*lane+1
  int t = s;
  for (; t + 8 <= e; t += 8) {
    uint2 e0 = edges[t + 0], e1 = edges[t + 1], e2 = edges[t + 2], e3 = edges[t + 3];
    uint2 e4 = edges[t + 4], e5 = edges[t + 5], e6 = edges[t + 6], e7 = edges[t + 7];
    uint u0 = h[(size_t)e0.x * 64 + lane];
    uint u1 = h[(size_t)e1.x * 64 + lane];
    uint u2 = h[(size_t)e2.x * 64 + lane];
    uint u3 = h[(size_t)e3.x * 64 + lane];
    uint u4 = h[(size_t)e4.x * 64 + lane];
    uint u5 = h[(size_t)e5.x * 64 + lane];
    uint u6 = h[(size_t)e6.x * 64 + lane];
    uint u7 = h[(size_t)e7.x * 64 + lane];
    float v0 = __uint_as_float(e0.y), v1 = __uint_as_float(e1.y);
    float v2 = __uint_as_float(e2.y), v3 = __uint_as_float(e3.y);
    float v4 = __uint_as_float(e4.y), v5 = __uint_as_float(e5.y);
    float v6 = __uint_as_float(e6.y), v7 = __uint_as_float(e7.y);
    a0 = fmaf(v0, bf_lo(u0), a0); a1 = fmaf(v0, bf_hi(u0), a1);
    a0 = fmaf(v1, bf_lo(u1), a0); a1 = fmaf(v1, bf_hi(u1), a1);
    a0 = fmaf(v2, bf_lo(u2), a0); a1 = fmaf(v2, bf_hi(u2), a1);
    a0 = fmaf(v3, bf_lo(u3), a0); a1 = fmaf(v3, bf_hi(u3), a1);
    a0 = fmaf(v4, bf_lo(u4), a0); a1 = fmaf(v4, bf_hi(u4), a1);
    a0 = fmaf(v5, bf_lo(u5), a0); a1 = fmaf(v5, bf_hi(u5), a1);
    a0 = fmaf(v6, bf_lo(u6), a0); a1 = fmaf(v6, bf_hi(u6), a1);
    a0 = fmaf(v7, bf_lo(u7), a0); a1 = fmaf(v7, bf_hi(u7), a1);
  }
  for (; t + 4 <= e; t += 4) {
    uint2 e0 = edges[t + 0], e1 = edges[t + 1], e2 = edges[t + 2], e3 = edges[t + 3];
    uint u0 = h[(size_t)e0.x * 64 + lane];
    uint u1 = h[(size_t)e1.x * 64 + lane];
    uint u2 = h[(size_t)e2.x * 64 + lane];
    uint u3 = h[(size_t)e3.x * 64 + lane];
    float v0 = __uint_as_float(e0.y), v1 = __uint_as_float(e1.y);
    float v2 = __uint_as_float(e2.y), v3 = __uint_as_float(e3.y);
    a0 = fmaf(v0, bf_lo(u0), a0); a1 = fmaf(v0, bf_hi(u0), a1);
    a0 = fmaf(v1, bf_lo(u1), a0); a1 = fmaf(v1, bf_hi(u1), a1);
    a0 = fmaf(v2, bf_lo(u2), a0); a1 = fmaf(v2, bf_hi(u2), a1);
    a0 = fmaf(v3, bf_lo(u3), a0); a1 = fmaf(v3, bf_hi(u3), a1);
  }
  for (; t < e; ++t) {
    uint2 e0 = edges[t];
    uint u0 = h[(size_t)e0.x * 64 + lane];
    float v0 = __uint_as_float(e0.y);
    a0 = fmaf(v0, bf_lo(u0), a0); a1 = fmaf(v0, bf_hi(u0), a1);
  }
  float2 bb = ((const float2*)b1)[lane];
  float r0 = fmaxf(a0 + bb.x, 0.f);
  float r1 = fmaxf(a1 + bb.y, 0.f);
  agg[(size_t)r * 64 + lane] = pkbf(r0, r1);
}

// ---------------- SPMM2 + b2: one wave/row, 2 half-wave workers, 8 in flight ----------------
__global__ __launch_bounds__(256)
void k_spmm2(const int* __restrict__ rp, const uint2* __restrict__ edges,
             const uint* __restrict__ h2, const float* __restrict__ b2,
             float* __restrict__ out, int n) {
  int r = blockIdx.x * 4 + (threadIdx.x >> 6);
  if (r >= n) return;
  int lane = threadIdx.x & 63;
  int half = lane >> 5;
  int fl = lane & 31;                  // feat pair 2*fl, 2*fl+1
  int s = rp[r], e = rp[r + 1];
  float a0 = 0.f, a1 = 0.f;
  int t = s + half;
  for (; t + 6 < e; t += 8) {
    uint2 e0 = edges[t], e1 = edges[t + 2], e2 = edges[t + 4], e3 = edges[t + 6];
    uint u0 = h2[(size_t)e0.x * 32 + fl];
    uint u1 = h2[(size_t)e1.x * 32 + fl];
    uint u2 = h2[(size_t)e2.x * 32 + fl];
    uint u3 = h2[(size_t)e3.x * 32 + fl];
    float v0 = __uint_as_float(e0.y), v1 = __uint_as_float(e1.y);
    float v2 = __uint_as_float(e2.y), v3 = __uint_as_float(e3.y);
    a0 = fmaf(v0, bf_lo(u0), a0); a1 = fmaf(v0, bf_hi(u0), a1);
    a0 = fmaf(v1, bf_lo(u1), a0); a1 = fmaf(v1, bf_hi(u1), a1);
    a0 = fmaf(v2, bf_lo(u2), a0); a1 = fmaf(v2, bf_hi(u2), a1);
    a0 = fmaf(v3, bf_lo(u3), a0); a1 = fmaf(v3, bf_hi(u3), a1);
  }
  for (; t < e; t += 2) {
    uint2 e0 = edges[t];
    uint u0 = h2[(size_t)e0.x * 32 + fl];
    float v0 = __uint_as_float(e0.y);
    a0 = fmaf(v0, bf_lo(u0), a0); a1 = fmaf(v0, bf_hi(u0), a1);
  }
  a0 += __shfl_xor(a0, 32);
  a1 += __shfl_xor(a1, 32);
  if (half == 0) {
    float2 bb = ((const float2*)b2)[fl];
    ((float2*)out)[(size_t)r * 32 + fl] = make_float2(a0 + bb.x, a1 + bb.y);
  }
}

extern "C" void kernel_launch(void* const* d_in, const int* in_sizes, int n_in,
                              void* d_out, int out_size, void* d_ws, size_t ws_size,
                              hipStream_t stream) {
  const float* x        = (const float*)d_in[0];
  const float* w1       = (const float*)d_in[1];
  const float* b1       = (const float*)d_in[2];
  const float* w2       = (const float*)d_in[3];
  const float* b2       = (const float*)d_in[4];
  const int*   adj_row  = (const int*)d_in[5];
  const int*   adj_col  = (const int*)d_in[6];
  const float* adj_vals = (const float*)d_in[7];
  float* out = (float*)d_out;

  const int N  = in_sizes[0] / 256;   // 100000
  const int NE = in_sizes[5];         // 1600000

  const int NB   = (N + BW - 1) / BW;          // 782 row-buckets
  const int NBLK = (NE + CHUNK - 1) / CHUNK;   // 782 partition chunks

  char* p = (char*)d_ws;
  auto carve = [&](size_t bytes) {
    char* r = p;
    p += (bytes + 255) & ~(size_t)255;
    return (void*)r;
  };
  uint*   h      = (uint*)  carve((size_t)N * 64 * 4);          // bf16 [N][128]
  uint*   agg    = (uint*)  carve((size_t)N * 64 * 4);          // bf16 [N][128]
  uint2*  edges  = (uint2*) carve((size_t)NE * 8);              // {col, val}
  uint2*  tmp    = (uint2*) carve((size_t)NE * 8);              // bucket-partitioned
  int*    rp     = (int*)   carve(((size_t)NB * BW + 64) * 4);  // row ptrs (rp[N] valid)
  int*    bh     = (int*)   carve((size_t)NB * NBLK * 4);       // [bucket][chunk] hist
  int*    tot    = (int*)   carve((size_t)NB * 4 + 256);
  int*    bbase  = (int*)   carve((size_t)NB * 4 + 256);
  ushort* w1t    = (ushort*)carve(128 * 256 * 2);               // bf16 [128][256]
  ushort* w2t    = (ushort*)carve(64 * 128 * 2);                // bf16 [64][128]
  uint*   h2     = h;                                           // h dead after spmm1

  hipLaunchKernelGGL(k_tr_w,    dim3(160),             dim3(256),  0, stream, w1, w1t, w2, w2t);
  hipLaunchKernelGGL(k_p1_hist, dim3(NBLK),            dim3(256),  0, stream, adj_row, bh, NB, NBLK, NE);
  hipLaunchKernelGGL(k_p2a,     dim3(NB),              dim3(1024), 0, stream, bh, tot, NBLK);
  hipLaunchKernelGGL(k_p2b,     dim3(1),               dim3(1024), 0, stream, tot, bbase, NB);
  hipLaunchKernelGGL(k_p3_part, dim3(NBLK),            dim3(256),  0, stream,
                     adj_row, adj_col, adj_vals, bh, bbase, tmp, NB, NBLK, NE);
  hipLaunchKernelGGL(k_p4_sort, dim3(NB),              dim3(256),  0, stream,
                     tmp, bbase, rp, edges, NE, NB);

  hipLaunchKernelGGL(gemm1_mfma, dim3((N + 127) / 128), dim3(256), 0, stream, x, w1t, h, N);
  hipLaunchKernelGGL(k_spmm1,    dim3((N + 3) / 4),     dim3(256), 0, stream,
                     rp, edges, h, b1, agg, N);
  hipLaunchKernelGGL(gemm2_mfma, dim3((N + 127) / 128), dim3(256), 0, stream, agg, w2t, h2, N);
  hipLaunchKernelGGL(k_spmm2,    dim3((N + 3) / 4),     dim3(256), 0, stream,
                     rp, edges, h2, b2, out, N);
}

// Round 9
// 413.291 us; speedup vs baseline: 1.3508x; 1.0031x over previous
//
#include <hip/hip_runtime.h>

// GCN forward: h = relu(spmm(x@w1)+b1); out = spmm(h@w2)+b2
// CSR built per launch: bucket partition (128-row buckets, 2048-edge chunks)
// + per-bucket counting sort that also emits row pointers.
// Intermediates bf16-packed. GEMMs: no-LDS register MFMA, N-split across waves
// for occupancy (latency-bound fix, r7).

typedef unsigned int uint;
typedef unsigned short ushort;
using bf16x8 = __attribute__((ext_vector_type(8))) short;
using f32x4  = __attribute__((ext_vector_type(4))) float;

union U8 { bf16x8 v; uint4 q; };

#define CHUNK 2048    // edges per partition block
#define BW    128     // rows per bucket

__device__ inline uint f2bf(float f) {
  uint u = __float_as_uint(f);
  return (u + 0x7fffu + ((u >> 16) & 1u)) >> 16;   // RNE
}
__device__ inline uint pkbf(float lo, float hi) { return f2bf(lo) | (f2bf(hi) << 16); }
__device__ inline float bf_lo(uint u) { return __uint_as_float(u << 16); }
__device__ inline float bf_hi(uint u) { return __uint_as_float(u & 0xffff0000u); }

// ---------------- weight transpose+cast (fused, tiny) ----------------
__global__ void k_tr_w(const float* __restrict__ w1, ushort* __restrict__ w1t,
                       const float* __restrict__ w2, ushort* __restrict__ w2t) {
  int idx = blockIdx.x * 256 + threadIdx.x;
  if (idx < 32768) {               // 256x128
    int k = idx >> 7, n = idx & 127;
    w1t[n * 256 + k] = (ushort)f2bf(w1[idx]);
  } else {
    int j = idx - 32768;           // 128x64
    if (j < 8192) {
      int k = j >> 6, n = j & 63;
      w2t[n * 128 + k] = (ushort)f2bf(w2[j]);
    }
  }
}

// ---------------- P1: per-chunk histogram over row-buckets ----------------
__global__ __launch_bounds__(256)
void k_p1_hist(const int* __restrict__ row, int* __restrict__ bh,
               int nb, int nblk, int ne) {
  __shared__ int hist[1024];
  int t = threadIdx.x;
  for (int i = t; i < nb; i += 256) hist[i] = 0;
  __syncthreads();
  int base = blockIdx.x * CHUNK;
  int end  = min(base + CHUNK, ne);
  for (int i = base + t; i < end; i += 256)
    atomicAdd(&hist[row[i] >> 7], 1);
  __syncthreads();
  for (int i = t; i < nb; i += 256)
    bh[(size_t)i * nblk + blockIdx.x] = hist[i];   // transposed: [bucket][chunk]
}

// ---------------- P2a: per-bucket exclusive scan across chunks ----------------
__global__ __launch_bounds__(1024)
void k_p2a(int* __restrict__ bh, int* __restrict__ tot, int nblk) {
  __shared__ int sd[1024];
  int g = blockIdx.x, t = threadIdx.x;
  int v = (t < nblk) ? bh[(size_t)g * nblk + t] : 0;
  sd[t] = v;
  __syncthreads();
  for (int o = 1; o < 1024; o <<= 1) {
    int x = (t >= o) ? sd[t - o] : 0;
    __syncthreads();
    sd[t] += x;
    __syncthreads();
  }
  if (t < nblk) bh[(size_t)g * nblk + t] = sd[t] - v;
  if (t == 1023) tot[g] = sd[1023];
}

// ---------------- P2b: exclusive scan of bucket totals -> bucketBase ----------------
__global__ __launch_bounds__(1024)
void k_p2b(const int* __restrict__ tot, int* __restrict__ bucketBase, int nb) {
  __shared__ int sd[1024];
  int t = threadIdx.x;
  int v = (t < nb) ? tot[t] : 0;
  sd[t] = v;
  __syncthreads();
  for (int o = 1; o < 1024; o <<= 1) {
    int x = (t >= o) ? sd[t - o] : 0;
    __syncthreads();
    sd[t] += x;
    __syncthreads();
  }
  if (t < nb) bucketBase[t] = sd[t] - v;
}

// ---------------- P3: partition edges into bucket segments ----------------
__global__ __launch_bounds__(256)
void k_p3_part(const int* __restrict__ row, const int* __restrict__ col,
               const float* __restrict__ vals, const int* __restrict__ bh,
               const int* __restrict__ bucketBase, uint2* __restrict__ tmp,
               int nb, int nblk, int ne) {
  __shared__ int cur[1024];
  int t = threadIdx.x, blk = blockIdx.x;
  for (int i = t; i < nb; i += 256)
    cur[i] = bucketBase[i] + bh[(size_t)i * nblk + blk];
  __syncthreads();
  int base = blk * CHUNK;
  int end  = min(base + CHUNK, ne);
  for (int i = base + t; i < end; i += 256) {
    int r = row[i];
    int p = atomicAdd(&cur[r >> 7], 1);
    tmp[p] = make_uint2(((uint)(r & 127) << 17) | (uint)col[i],
                        __float_as_uint(vals[i]));
  }
}

// ---------------- P4: per-bucket counting sort; emits rp + final edges ----------------
__global__ __launch_bounds__(256)
void k_p4_sort(const uint2* __restrict__ tmp, const int* __restrict__ bucketBase,
               int* __restrict__ rp, uint2* __restrict__ edges,
               int ne, int nb) {
  __shared__ int hist[128];
  __shared__ int cur[128];
  int g = blockIdx.x, t = threadIdx.x;
  int base = bucketBase[g];
  int end  = (g + 1 < nb) ? bucketBase[g + 1] : ne;
  if (t < 128) hist[t] = 0;
  __syncthreads();
  for (int i = base + t; i < end; i += 256)
    atomicAdd(&hist[tmp[i].x >> 17], 1);
  __syncthreads();
  int v = (t < 128) ? hist[t] : 0;
  for (int o = 1; o < 128; o <<= 1) {
    int x = (t < 128 && t >= o) ? hist[t - o] : 0;
    __syncthreads();
    if (t < 128) hist[t] += x;
    __syncthreads();
  }
  if (t < 128) {
    int excl = hist[t] - v;
    rp[(g << 7) + t] = base + excl;   // rows >= N get rp = segment end (= NE at tail)
    cur[t] = base + excl;
  }
  __syncthreads();
  for (int i = base + t; i < end; i += 256) {
    uint2 ev = tmp[i];
    int lr = (int)(ev.x >> 17);
    int p = atomicAdd(&cur[lr], 1);
    edges[p] = make_uint2(ev.x & 0x1FFFFu, ev.y);
  }
}

// ---------------- GEMM1 (MFMA): h_bf16[M,128] = x[M,256] @ w1[256,128] ----------------
// Block: 64 rows x 128 cols; wave = 32 rows x 64 cols (N-split for occupancy).
__global__ __launch_bounds__(256)
void gemm1_mfma(const float* __restrict__ A, const ushort* __restrict__ Bt,
                uint* __restrict__ C, int M) {
  const int tid  = threadIdx.x;
  const int wid  = tid >> 6;
  const int lane = tid & 63;
  const int lr   = lane & 15;
  const int lk   = lane >> 4;
  const int m0   = blockIdx.x * 64 + (wid >> 1) * 32;
  const int n0   = (wid & 1) * 64;            // col offset, 4 nf frags

  f32x4 acc[2][4];
#pragma unroll
  for (int mf = 0; mf < 2; ++mf)
#pragma unroll
    for (int nf = 0; nf < 4; ++nf) acc[mf][nf] = (f32x4){0.f, 0.f, 0.f, 0.f};

  const int row0 = min(m0 + lr,      M - 1);
  const int row1 = min(m0 + 16 + lr, M - 1);
  const float*  a0p = A + (size_t)row0 * 256 + lk * 8;
  const float*  a1p = A + (size_t)row1 * 256 + lk * 8;
  const ushort* bp  = Bt + (n0 + lr) * 256 + lk * 8;

#pragma unroll
  for (int kk = 0; kk < 8; ++kk) {
    float4 x0 = *(const float4*)(a0p + kk * 32);
    float4 x1 = *(const float4*)(a0p + kk * 32 + 4);
    float4 y0 = *(const float4*)(a1p + kk * 32);
    float4 y1 = *(const float4*)(a1p + kk * 32 + 4);
    U8 a0, a1;
    a0.q = make_uint4(pkbf(x0.x, x0.y), pkbf(x0.z, x0.w), pkbf(x1.x, x1.y), pkbf(x1.z, x1.w));
    a1.q = make_uint4(pkbf(y0.x, y0.y), pkbf(y0.z, y0.w), pkbf(y1.x, y1.y), pkbf(y1.z, y1.w));
    bf16x8 b[4];
#pragma unroll
    for (int nf = 0; nf < 4; ++nf)
      b[nf] = *(const bf16x8*)(bp + nf * 4096 + kk * 32);   // nf stride = 16 rows
#pragma unroll
    for (int nf = 0; nf < 4; ++nf) {
      acc[0][nf] = __builtin_amdgcn_mfma_f32_16x16x32_bf16(a0.v, b[nf], acc[0][nf], 0, 0, 0);
      acc[1][nf] = __builtin_amdgcn_mfma_f32_16x16x32_bf16(a1.v, b[nf], acc[1][nf], 0, 0, 0);
    }
  }

  const bool evenl = (lr & 1) == 0;
#pragma unroll
  for (int mf = 0; mf < 2; ++mf)
#pragma unroll
    for (int nf = 0; nf < 4; ++nf)
#pragma unroll
      for (int j = 0; j < 4; ++j) {
        float own = acc[mf][nf][j];
        float oth = __shfl_xor(own, 1);
        int row = m0 + mf * 16 + lk * 4 + j;
        if (evenl && row < M)
          C[(size_t)row * 64 + (n0 >> 1) + nf * 8 + (lr >> 1)] = pkbf(own, oth);
      }
}

// ---------------- GEMM2 (MFMA): h2_bf16[M,64] = agg_bf16[M,128] @ w2[128,64] ----------------
// Block: 64 rows x 64 cols; wave = 32 rows x 32 cols.
__global__ __launch_bounds__(256)
void gemm2_mfma(const uint* __restrict__ A, const ushort* __restrict__ Bt,
                uint* __restrict__ C, int M) {
  const int tid  = threadIdx.x;
  const int wid  = tid >> 6;
  const int lane = tid & 63;
  const int lr   = lane & 15;
  const int lk   = lane >> 4;
  const int m0   = blockIdx.x * 64 + (wid >> 1) * 32;
  const int n0   = (wid & 1) * 32;            // col offset, 2 nf frags

  f32x4 acc[2][2];
#pragma unroll
  for (int mf = 0; mf < 2; ++mf)
#pragma unroll
    for (int nf = 0; nf < 2; ++nf) acc[mf][nf] = (f32x4){0.f, 0.f, 0.f, 0.f};

  const int row0 = min(m0 + lr,      M - 1);
  const int row1 = min(m0 + 16 + lr, M - 1);
  const ushort* A16 = (const ushort*)A;
  const ushort* a0p = A16 + (size_t)row0 * 128 + lk * 8;
  const ushort* a1p = A16 + (size_t)row1 * 128 + lk * 8;
  const ushort* bp  = Bt + (n0 + lr) * 128 + lk * 8;

#pragma unroll
  for (int kk = 0; kk < 4; ++kk) {
    bf16x8 a0 = *(const bf16x8*)(a0p + kk * 32);
    bf16x8 a1 = *(const bf16x8*)(a1p + kk * 32);
    bf16x8 b[2];
#pragma unroll
    for (int nf = 0; nf < 2; ++nf)
      b[nf] = *(const bf16x8*)(bp + nf * 2048 + kk * 32);   // nf stride = 16 rows
#pragma unroll
    for (int nf = 0; nf < 2; ++nf) {
      acc[0][nf] = __builtin_amdgcn_mfma_f32_16x16x32_bf16(a0, b[nf], acc[0][nf], 0, 0, 0);
      acc[1][nf] = __builtin_amdgcn_mfma_f32_16x16x32_bf16(a1, b[nf], acc[1][nf], 0, 0, 0);
    }
  }

  const bool evenl = (lr & 1) == 0;
#pragma unroll
  for (int mf = 0; mf < 2; ++mf)
#pragma unroll
    for (int nf = 0; nf < 2; ++nf)
#pragma unroll
      for (int j = 0; j < 4; ++j) {
        float own = acc[mf][nf][j];
        float oth = __shfl_xor(own, 1);
        int row = m0 + mf * 16 + lk * 4 + j;
        if (evenl && row < M)
          C[(size_t)row * 32 + (n0 >> 1) + nf * 8 + (lr >> 1)] = pkbf(own, oth);
      }
}

// ---------------- SPMM1 + relu(+b1): one wave/row, 8 gathers in flight ----------------
__global__ __launch_bounds__(256)
void k_spmm1(const int* __restrict__ rp, const uint2* __restrict__ edges,
             const uint* __restrict__ h, const float* __restrict__ b1,
             uint* __restrict__ agg, int n) {
  int r = blockIdx.x * 4 + (threadIdx.x >> 6);
  if (r >= n) return;
  int lane = threadIdx.x & 63;
  int s = rp[r], e = rp[r + 1];
  float a0 = 0.f, a1 = 0.f;            // feats 2*lane, 2*lane+1
  int t = s;
  for (; t + 8 <= e; t += 8) {
    uint2 e0 = edges[t + 0], e1 = edges[t + 1], e2 = edges[t + 2], e3 = edges[t + 3];
    uint2 e4 = edges[t + 4], e5 = edges[t + 5], e6 = edges[t + 6], e7 = edges[t + 7];
    uint u0 = h[(size_t)e0.x * 64 + lane];
    uint u1 = h[(size_t)e1.x * 64 + lane];
    uint u2 = h[(size_t)e2.x * 64 + lane];
    uint u3 = h[(size_t)e3.x * 64 + lane];
    uint u4 = h[(size_t)e4.x * 64 + lane];
    uint u5 = h[(size_t)e5.x * 64 + lane];
    uint u6 = h[(size_t)e6.x * 64 + lane];
    uint u7 = h[(size_t)e7.x * 64 + lane];
    float v0 = __uint_as_float(e0.y), v1 = __uint_as_float(e1.y);
    float v2 = __uint_as_float(e2.y), v3 = __uint_as_float(e3.y);
    float v4 = __uint_as_float(e4.y), v5 = __uint_as_float(e5.y);
    float v6 = __uint_as_float(e6.y), v7 = __uint_as_float(e7.y);
    a0 = fmaf(v0, bf_lo(u0), a0); a1 = fmaf(v0, bf_hi(u0), a1);
    a0 = fmaf(v1, bf_lo(u1), a0); a1 = fmaf(v1, bf_hi(u1), a1);
    a0 = fmaf(v2, bf_lo(u2), a0); a1 = fmaf(v2, bf_hi(u2), a1);
    a0 = fmaf(v3, bf_lo(u3), a0); a1 = fmaf(v3, bf_hi(u3), a1);
    a0 = fmaf(v4, bf_lo(u4), a0); a1 = fmaf(v4, bf_hi(u4), a1);
    a0 = fmaf(v5, bf_lo(u5), a0); a1 = fmaf(v5, bf_hi(u5), a1);
    a0 = fmaf(v6, bf_lo(u6), a0); a1 = fmaf(v6, bf_hi(u6), a1);
    a0 = fmaf(v7, bf_lo(u7), a0); a1 = fmaf(v7, bf_hi(u7), a1);
  }
  for (; t + 4 <= e; t += 4) {
    uint2 e0 = edges[t + 0], e1 = edges[t + 1], e2 = edges[t + 2], e3 = edges[t + 3];
    uint u0 = h[(size_t)e0.x * 64 + lane];
    uint u1 = h[(size_t)e1.x * 64 + lane];
    uint u2 = h[(size_t)e2.x * 64 + lane];
    uint u3 = h[(size_t)e3.x * 64 + lane];
    float v0 = __uint_as_float(e0.y), v1 = __uint_as_float(e1.y);
    float v2 = __uint_as_float(e2.y), v3 = __uint_as_float(e3.y);
    a0 = fmaf(v0, bf_lo(u0), a0); a1 = fmaf(v0, bf_hi(u0), a1);
    a0 = fmaf(v1, bf_lo(u1), a0); a1 = fmaf(v1, bf_hi(u1), a1);
    a0 = fmaf(v2, bf_lo(u2), a0); a1 = fmaf(v2, bf_hi(u2), a1);
    a0 = fmaf(v3, bf_lo(u3), a0); a1 = fmaf(v3, bf_hi(u3), a1);
  }
  for (; t < e; ++t) {
    uint2 e0 = edges[t];
    uint u0 = h[(size_t)e0.x * 64 + lane];
    float v0 = __uint_as_float(e0.y);
    a0 = fmaf(v0, bf_lo(u0), a0); a1 = fmaf(v0, bf_hi(u0), a1);
  }
  float2 bb = ((const float2*)b1)[lane];
  float r0 = fmaxf(a0 + bb.x, 0.f);
  float r1 = fmaxf(a1 + bb.y, 0.f);
  agg[(size_t)r * 64 + lane] = pkbf(r0, r1);
}

// ---------------- SPMM2 + b2: one wave/row, 2 half-wave workers, 8 in flight ----------------
__global__ __launch_bounds__(256)
void k_spmm2(const int* __restrict__ rp, const uint2* __restrict__ edges,
             const uint* __restrict__ h2, const float* __restrict__ b2,
             float* __restrict__ out, int n) {
  int r = blockIdx.x * 4 + (threadIdx.x >> 6);
  if (r >= n) return;
  int lane = threadIdx.x & 63;
  int half = lane >> 5;
  int fl = lane & 31;                  // feat pair 2*fl, 2*fl+1
  int s = rp[r], e = rp[r + 1];
  float a0 = 0.f, a1 = 0.f;
  int t = s + half;
  for (; t + 6 < e; t += 8) {
    uint2 e0 = edges[t], e1 = edges[t + 2], e2 = edges[t + 4], e3 = edges[t + 6];
    uint u0 = h2[(size_t)e0.x * 32 + fl];
    uint u1 = h2[(size_t)e1.x * 32 + fl];
    uint u2 = h2[(size_t)e2.x * 32 + fl];
    uint u3 = h2[(size_t)e3.x * 32 + fl];
    float v0 = __uint_as_float(e0.y), v1 = __uint_as_float(e1.y);
    float v2 = __uint_as_float(e2.y), v3 = __uint_as_float(e3.y);
    a0 = fmaf(v0, bf_lo(u0), a0); a1 = fmaf(v0, bf_hi(u0), a1);
    a0 = fmaf(v1, bf_lo(u1), a0); a1 = fmaf(v1, bf_hi(u1), a1);
    a0 = fmaf(v2, bf_lo(u2), a0); a1 = fmaf(v2, bf_hi(u2), a1);
    a0 = fmaf(v3, bf_lo(u3), a0); a1 = fmaf(v3, bf_hi(u3), a1);
  }
  for (; t < e; t += 2) {
    uint2 e0 = edges[t];
    uint u0 = h2[(size_t)e0.x * 32 + fl];
    float v0 = __uint_as_float(e0.y);
    a0 = fmaf(v0, bf_lo(u0), a0); a1 = fmaf(v0, bf_hi(u0), a1);
  }
  a0 += __shfl_xor(a0, 32);
  a1 += __shfl_xor(a1, 32);
  if (half == 0) {
    float2 bb = ((const float2*)b2)[fl];
    ((float2*)out)[(size_t)r * 32 + fl] = make_float2(a0 + bb.x, a1 + bb.y);
  }
}

extern "C" void kernel_launch(void* const* d_in, const int* in_sizes, int n_in,
                              void* d_out, int out_size, void* d_ws, size_t ws_size,
                              hipStream_t stream) {
  const float* x        = (const float*)d_in[0];
  const float* w1       = (const float*)d_in[1];
  const float* b1       = (const float*)d_in[2];
  const float* w2       = (const float*)d_in[3];
  const float* b2       = (const float*)d_in[4];
  const int*   adj_row  = (const int*)d_in[5];
  const int*   adj_col  = (const int*)d_in[6];
  const float* adj_vals = (const float*)d_in[7];
  float* out = (float*)d_out;

  const int N  = in_sizes[0] / 256;   // 100000
  const int NE = in_sizes[5];         // 1600000

  const int NB   = (N + BW - 1) / BW;          // 782 row-buckets
  const int NBLK = (NE + CHUNK - 1) / CHUNK;   // 782 partition chunks

  char* p = (char*)d_ws;
  auto carve = [&](size_t bytes) {
    char* r = p;
    p += (bytes + 255) & ~(size_t)255;
    return (void*)r;
  };
  uint*   h      = (uint*)  carve((size_t)N * 64 * 4);          // bf16 [N][128]
  uint*   agg    = (uint*)  carve((size_t)N * 64 * 4);          // bf16 [N][128]
  uint2*  edges  = (uint2*) carve((size_t)NE * 8);              // {col, val}
  uint2*  tmp    = (uint2*) carve((size_t)NE * 8);              // bucket-partitioned
  int*    rp     = (int*)   carve(((size_t)NB * BW + 64) * 4);  // row ptrs (rp[N] valid)
  int*    bh     = (int*)   carve((size_t)NB * NBLK * 4);       // [bucket][chunk] hist
  int*    tot    = (int*)   carve((size_t)NB * 4 + 256);
  int*    bbase  = (int*)   carve((size_t)NB * 4 + 256);
  ushort* w1t    = (ushort*)carve(128 * 256 * 2);               // bf16 [128][256]
  ushort* w2t    = (ushort*)carve(64 * 128 * 2);                // bf16 [64][128]
  uint*   h2     = h;                                           // h dead after spmm1

  hipLaunchKernelGGL(k_tr_w,    dim3(160),             dim3(256),  0, stream, w1, w1t, w2, w2t);
  hipLaunchKernelGGL(k_p1_hist, dim3(NBLK),            dim3(256),  0, stream, adj_row, bh, NB, NBLK, NE);
  hipLaunchKernelGGL(k_p2a,     dim3(NB),              dim3(1024), 0, stream, bh, tot, NBLK);
  hipLaunchKernelGGL(k_p2b,     dim3(1),               dim3(1024), 0, stream, tot, bbase, NB);
  hipLaunchKernelGGL(k_p3_part, dim3(NBLK),            dim3(256),  0, stream,
                     adj_row, adj_col, adj_vals, bh, bbase, tmp, NB, NBLK, NE);
  hipLaunchKernelGGL(k_p4_sort, dim3(NB),              dim3(256),  0, stream,
                     tmp, bbase, rp, edges, NE, NB);

  hipLaunchKernelGGL(gemm1_mfma, dim3((N + 63) / 64),  dim3(256), 0, stream, x, w1t, h, N);
  hipLaunchKernelGGL(k_spmm1,    dim3((N + 3) / 4),    dim3(256), 0, stream,
                     rp, edges, h, b1, agg, N);
  hipLaunchKernelGGL(gemm2_mfma, dim3((N + 63) / 64),  dim3(256), 0, stream, agg, w2t, h2, N);
  hipLaunchKernelGGL(k_spmm2,    dim3((N + 3) / 4),    dim3(256), 0, stream,
                     rp, edges, h2, b2, out, N);
}